// Round 4
// baseline (10283.471 us; speedup 1.0000x reference)
//
#include <hip/hip_runtime.h>
#include <hip/hip_bf16.h>
#include <math.h>

#define B_ 128
#define S_ 1024
#define H_ 512
#define E_ 512
#define T_ 64
#define L_ 128
#define G4H 2048  // 4*H

typedef __attribute__((ext_vector_type(8))) short bf16x8;
typedef __attribute__((ext_vector_type(4))) float f32x4;

__device__ inline float sigmoidf_(float x) { return 1.f / (1.f + expf(-x)); }
__device__ inline float fast_tanhf_(float x) {
    float e = __expf(2.f * x);
    return 1.f - 2.f / (e + 1.f);
}
__device__ inline unsigned f2bf1(float f) {
    unsigned u = __float_as_uint(f);
    return (u + 0x7fffu + ((u >> 16) & 1u)) >> 16;
}

// ---------------------------------------------------------------------------
// Big fp32 GEMM: tile 128x128, 256 thr, 8x8/thread.  (proven R2 kernel)
// ---------------------------------------------------------------------------
__global__ __launch_bounds__(256) void gemm128(
    const float* __restrict__ A, int lda,
    const float* __restrict__ W, int ldw,
    const float* __restrict__ bias,
    const float* __restrict__ Cinit, int ldci,
    float* __restrict__ C, int ldc,
    int K, int act, int perm)
{
    __shared__ float As[16][128];
    __shared__ float Ws[16][128];
    const int m0 = blockIdx.x * 128;
    const int n0 = blockIdx.y * 128;
    const int t = threadIdx.x;
    const int tx = t & 15;
    const int ty = t >> 4;
    const int lr = t >> 1;
    const int lk = (t & 1) * 8;

    float acc[8][8] = {};

    for (int k0 = 0; k0 < K; k0 += 16) {
        float4 a0 = *reinterpret_cast<const float4*>(A + (size_t)(m0 + lr) * lda + k0 + lk);
        float4 a1 = *reinterpret_cast<const float4*>(A + (size_t)(m0 + lr) * lda + k0 + lk + 4);
        float4 w0 = *reinterpret_cast<const float4*>(W + (size_t)(n0 + lr) * ldw + k0 + lk);
        float4 w1 = *reinterpret_cast<const float4*>(W + (size_t)(n0 + lr) * ldw + k0 + lk + 4);
        As[lk + 0][lr] = a0.x; As[lk + 1][lr] = a0.y; As[lk + 2][lr] = a0.z; As[lk + 3][lr] = a0.w;
        As[lk + 4][lr] = a1.x; As[lk + 5][lr] = a1.y; As[lk + 6][lr] = a1.z; As[lk + 7][lr] = a1.w;
        Ws[lk + 0][lr] = w0.x; Ws[lk + 1][lr] = w0.y; Ws[lk + 2][lr] = w0.z; Ws[lk + 3][lr] = w0.w;
        Ws[lk + 4][lr] = w1.x; Ws[lk + 5][lr] = w1.y; Ws[lk + 6][lr] = w1.z; Ws[lk + 7][lr] = w1.w;
        __syncthreads();
#pragma unroll
        for (int kk = 0; kk < 16; ++kk) {
            float a[8], b[8];
#pragma unroll
            for (int i = 0; i < 8; ++i) a[i] = As[kk][ty * 8 + i];
#pragma unroll
            for (int j = 0; j < 8; ++j) b[j] = Ws[kk][tx * 8 + j];
#pragma unroll
            for (int i = 0; i < 8; ++i)
#pragma unroll
                for (int j = 0; j < 8; ++j) acc[i][j] = fmaf(a[i], b[j], acc[i][j]);
        }
        __syncthreads();
    }

#pragma unroll
    for (int i = 0; i < 8; ++i) {
        const int m = m0 + ty * 8 + i;
        size_t crow;
        if (perm) { int bb = m & 127, tt = m >> 7; crow = ((size_t)bb * T_ + tt) * ldc; }
        else crow = (size_t)m * ldc;
#pragma unroll
        for (int j = 0; j < 8; ++j) {
            const int n = n0 + tx * 8 + j;
            float v = acc[i][j];
            if (bias)  v += bias[n];
            if (Cinit) v += Cinit[(size_t)m * ldci + n];
            if (act == 1) v = tanhf(v);
            C[crow + n] = v;
        }
    }
}

// ---------------------------------------------------------------------------
// ctx GEMM, fp32-accurate via bf16 split MFMA (Markidis 3-product):
// C = Ah*Bh + Al*Bh + Ah*Bl  with X = Xh + Xl (bf16 hi/lo).  Dropped Al*Bl
// term <= 2^-18 relative.  fp32 in, fp32 out.  Tile 128x128, 4 waves, BK=32.
// ---------------------------------------------------------------------------
#define LDP 40  // 32 + 8 pad (shorts per LDS row); 80B rows -> 2-way bank alias only
__global__ __launch_bounds__(256) void gemm_ctx_split(
    const float* __restrict__ A,    // [M][512]
    const float* __restrict__ W,    // [512][512]
    const float* __restrict__ bias, // [512]
    float* __restrict__ C)          // [M][512]
{
    __shared__ unsigned short Ah[128 * LDP];
    __shared__ unsigned short Al[128 * LDP];
    __shared__ unsigned short Bh[128 * LDP];
    __shared__ unsigned short Bl[128 * LDP];
    const int n0 = blockIdx.x * 128;
    const int m0 = blockIdx.y * 128;
    const int t = threadIdx.x;
    const int lane = t & 63, wv = t >> 6;
    const int wr = wv >> 1, wc = wv & 1;
    const int row = t >> 1, koff = (t & 1) * 16;

    f32x4 acc[4][4] = {};

    for (int kt = 0; kt < 512; kt += 32) {
        float av[16], wvv[16];
        {
            const float* ap = A + (size_t)(m0 + row) * 512 + kt + koff;
            const float* wp = W + (size_t)(n0 + row) * 512 + kt + koff;
#pragma unroll
            for (int q = 0; q < 4; ++q) {
                *reinterpret_cast<float4*>(&av[q * 4]) = *reinterpret_cast<const float4*>(ap + q * 4);
                *reinterpret_cast<float4*>(&wvv[q * 4]) = *reinterpret_cast<const float4*>(wp + q * 4);
            }
        }
        unsigned short ah[16], al[16], bh[16], bl[16];
#pragma unroll
        for (int e = 0; e < 16; ++e) {
            unsigned ha = f2bf1(av[e]);
            float hf = __uint_as_float(ha << 16);
            ah[e] = (unsigned short)ha;
            al[e] = (unsigned short)f2bf1(av[e] - hf);
            unsigned hw = f2bf1(wvv[e]);
            float hwf = __uint_as_float(hw << 16);
            bh[e] = (unsigned short)hw;
            bl[e] = (unsigned short)f2bf1(wvv[e] - hwf);
        }
        __syncthreads();
        *reinterpret_cast<uint4*>(&Ah[row * LDP + koff])     = *reinterpret_cast<uint4*>(&ah[0]);
        *reinterpret_cast<uint4*>(&Ah[row * LDP + koff + 8]) = *reinterpret_cast<uint4*>(&ah[8]);
        *reinterpret_cast<uint4*>(&Al[row * LDP + koff])     = *reinterpret_cast<uint4*>(&al[0]);
        *reinterpret_cast<uint4*>(&Al[row * LDP + koff + 8]) = *reinterpret_cast<uint4*>(&al[8]);
        *reinterpret_cast<uint4*>(&Bh[row * LDP + koff])     = *reinterpret_cast<uint4*>(&bh[0]);
        *reinterpret_cast<uint4*>(&Bh[row * LDP + koff + 8]) = *reinterpret_cast<uint4*>(&bh[8]);
        *reinterpret_cast<uint4*>(&Bl[row * LDP + koff])     = *reinterpret_cast<uint4*>(&bl[0]);
        *reinterpret_cast<uint4*>(&Bl[row * LDP + koff + 8]) = *reinterpret_cast<uint4*>(&bl[8]);
        __syncthreads();

        bf16x8 fah[4], fal[4], fbh[4], fbl[4];
        const int kq = (lane >> 4) * 8;
#pragma unroll
        for (int i = 0; i < 4; ++i) {
            const int ar = wr * 64 + i * 16 + (lane & 15);
            const int br = wc * 64 + i * 16 + (lane & 15);
            fah[i] = *reinterpret_cast<const bf16x8*>(&Ah[ar * LDP + kq]);
            fal[i] = *reinterpret_cast<const bf16x8*>(&Al[ar * LDP + kq]);
            fbh[i] = *reinterpret_cast<const bf16x8*>(&Bh[br * LDP + kq]);
            fbl[i] = *reinterpret_cast<const bf16x8*>(&Bl[br * LDP + kq]);
        }
#pragma unroll
        for (int i = 0; i < 4; ++i)
#pragma unroll
            for (int j = 0; j < 4; ++j) {
                acc[i][j] = __builtin_amdgcn_mfma_f32_16x16x32_bf16(fah[i], fbh[j], acc[i][j], 0, 0, 0);
                acc[i][j] = __builtin_amdgcn_mfma_f32_16x16x32_bf16(fal[i], fbh[j], acc[i][j], 0, 0, 0);
                acc[i][j] = __builtin_amdgcn_mfma_f32_16x16x32_bf16(fah[i], fbl[j], acc[i][j], 0, 0, 0);
            }
    }

#pragma unroll
    for (int i = 0; i < 4; ++i)
#pragma unroll
        for (int j = 0; j < 4; ++j) {
            const int n = n0 + wc * 64 + j * 16 + (lane & 15);
            const float bs = bias[n];
#pragma unroll
            for (int r = 0; r < 4; ++r) {
                const int m = m0 + wr * 64 + i * 16 + (lane >> 4) * 4 + r;
                C[(size_t)m * 512 + n] = acc[i][j][r] + bs;
            }
        }
}

// ---------------------------------------------------------------------------
// Small-M GEMM with split-K (proven R2 kernel)
// ---------------------------------------------------------------------------
__global__ __launch_bounds__(256) void gemm_stepk(
    const float* __restrict__ A, int lda,
    const float* __restrict__ W, int ldw,
    float* __restrict__ P, int N, int Kc)
{
    __shared__ float As[16][128];
    __shared__ float Ws[16][64];
    const int n0 = blockIdx.x * 64;
    const int k0 = blockIdx.y * Kc;
    const int t = threadIdx.x;
    const int tx = t & 15;
    const int ty = t >> 4;
    const int ar = t >> 1, akq = (t & 1) * 8;
    const int wr = t >> 2, wkq = (t & 3) * 4;

    float acc[8][4] = {};

    for (int kb = 0; kb < Kc; kb += 16) {
        float4 a0 = *reinterpret_cast<const float4*>(A + (size_t)ar * lda + k0 + kb + akq);
        float4 a1 = *reinterpret_cast<const float4*>(A + (size_t)ar * lda + k0 + kb + akq + 4);
        float4 w0 = *reinterpret_cast<const float4*>(W + (size_t)(n0 + wr) * ldw + k0 + kb + wkq);
        As[akq + 0][ar] = a0.x; As[akq + 1][ar] = a0.y; As[akq + 2][ar] = a0.z; As[akq + 3][ar] = a0.w;
        As[akq + 4][ar] = a1.x; As[akq + 5][ar] = a1.y; As[akq + 6][ar] = a1.z; As[akq + 7][ar] = a1.w;
        Ws[wkq + 0][wr] = w0.x; Ws[wkq + 1][wr] = w0.y; Ws[wkq + 2][wr] = w0.z; Ws[wkq + 3][wr] = w0.w;
        __syncthreads();
#pragma unroll
        for (int kk = 0; kk < 16; ++kk) {
            float a[8], b[4];
#pragma unroll
            for (int i = 0; i < 8; ++i) a[i] = As[kk][ty * 8 + i];
#pragma unroll
            for (int j = 0; j < 4; ++j) b[j] = Ws[kk][tx * 4 + j];
#pragma unroll
            for (int i = 0; i < 8; ++i)
#pragma unroll
                for (int j = 0; j < 4; ++j) acc[i][j] = fmaf(a[i], b[j], acc[i][j]);
        }
        __syncthreads();
    }

#pragma unroll
    for (int i = 0; i < 8; ++i) {
        const int m = ty * 8 + i;
#pragma unroll
        for (int j = 0; j < 4; ++j)
            P[((size_t)blockIdx.y * 128 + m) * N + n0 + tx * 4 + j] = acc[i][j];
    }
}

// ---------------------------------------------------------------------------
__global__ void k_embed(const float* __restrict__ dec_in, const int* __restrict__ labels,
                        const float* __restrict__ emb, float* __restrict__ X)
{
    size_t total = (size_t)T_ * B_ * E_;
    for (size_t i = (size_t)blockIdx.x * blockDim.x + threadIdx.x; i < total;
         i += (size_t)gridDim.x * blockDim.x) {
        int e = (int)(i % E_);
        int b = (int)((i / E_) % B_);
        int t = (int)(i / ((size_t)E_ * B_));
        float v;
        if (t == 0) v = dec_in[b * E_ + e];
        else {
            int lab = labels[b * T_ + (t - 1)];
            v = emb[(size_t)lab * E_ + e];
        }
        X[i] = v;
    }
}

__global__ void k_init(const float* __restrict__ h0, const float* __restrict__ c0,
                       const float* __restrict__ b_ih, const float* __restrict__ b_hh,
                       float* __restrict__ hbuf, float* __restrict__ cbuf, float* __restrict__ bsum)
{
    int i = blockIdx.x * blockDim.x + threadIdx.x;
    hbuf[i] = h0[i];
    cbuf[i] = c0[i];
    if (i < G4H) bsum[i] = b_ih[i] + b_hh[i];
}

// LSTM pointwise from 4 gate partials + xproj[t]
__global__ __launch_bounds__(256) void k_lstm(const float* __restrict__ Pg,
                                              const float* __restrict__ xproj_t,
                                              float* __restrict__ cbuf, float* __restrict__ cat1)
{
    int i = blockIdx.x * blockDim.x + threadIdx.x;   // B*H
    int b = i >> 9, h = i & 511;
    const float* p0 = Pg + (size_t)b * G4H;
    const float* p1 = Pg + (size_t)(128 + b) * G4H;
    const float* p2 = Pg + (size_t)(256 + b) * G4H;
    const float* p3 = Pg + (size_t)(384 + b) * G4H;
    const float* xp = xproj_t + (size_t)b * G4H;
    float ig = sigmoidf_(p0[h] + p1[h] + p2[h] + p3[h] + xp[h]);
    float fg = sigmoidf_(p0[h + 512] + p1[h + 512] + p2[h + 512] + p3[h + 512] + xp[h + 512]);
    float gg = tanhf(p0[h + 1024] + p1[h + 1024] + p2[h + 1024] + p3[h + 1024] + xp[h + 1024]);
    float og = sigmoidf_(p0[h + 1536] + p1[h + 1536] + p2[h + 1536] + p3[h + 1536] + xp[h + 1536]);
    float c = fg * cbuf[i] + ig * gg;
    cbuf[i] = c;
    cat1[b * 1024 + 512 + h] = og * tanhf(c);
}

// ---------------------------------------------------------------------------
// Attention (fp32 ctx, proven R2 kernel): block (b, quarter) = 256 s-values.
// ---------------------------------------------------------------------------
__global__ __launch_bounds__(512) void k_attn(const float* __restrict__ ctx,
    const float* __restrict__ Pa, const float* __restrict__ b_ain,
    const float* __restrict__ Vv,
    float* __restrict__ pm, float* __restrict__ pl, float* __restrict__ pw)
{
    int blk = blockIdx.x;
    int b = blk >> 2, q = blk & 3;
    int tid = threadIdx.x, lane = tid & 63, wv = tid >> 6;

    __shared__ float inp_sh[512];
    inp_sh[tid] = Pa[(size_t)b * 512 + tid]
                + Pa[(size_t)(128 + b) * 512 + tid]
                + Pa[(size_t)(256 + b) * 512 + tid]
                + Pa[(size_t)(384 + b) * 512 + tid]
                + b_ain[tid];
    __syncthreads();

    float inpr[8], vr[8];
    {
        const float4* v4 = reinterpret_cast<const float4*>(Vv) + lane * 2;
        *(float4*)&vr[0] = v4[0];   *(float4*)&vr[4] = v4[1];
#pragma unroll
        for (int k = 0; k < 8; ++k) inpr[k] = inp_sh[lane * 8 + k];
    }
    const float* cbase = ctx + (size_t)b * S_ * H_ + (size_t)(q * 256) * H_;

    float m = -INFINITY, l = 0.f, w[8] = {};
    for (int si = 0; si < 32; ++si) {
        int s = wv * 32 + si;
        const float4* cp = reinterpret_cast<const float4*>(cbase + (size_t)s * H_) + lane * 2;
        float c8[8];
        *(float4*)&c8[0] = cp[0]; *(float4*)&c8[4] = cp[1];
        float t = 0.f;
#pragma unroll
        for (int k = 0; k < 8; ++k) t = fmaf(fast_tanhf_(inpr[k] + c8[k]), vr[k], t);
#pragma unroll
        for (int off = 32; off > 0; off >>= 1) t += __shfl_xor(t, off);
        float mn = fmaxf(m, t);
        float sc = __expf(m - mn);
        float p  = __expf(t - mn);
        l = l * sc + p;
#pragma unroll
        for (int k = 0; k < 8; ++k) w[k] = w[k] * sc + p * c8[k];
        m = mn;
    }

    __shared__ float wl[8 * 512];
    __shared__ float ml[8], ll[8];
#pragma unroll
    for (int k = 0; k < 8; ++k) wl[wv * 512 + lane * 8 + k] = w[k];
    if (lane == 0) { ml[wv] = m; ll[wv] = l; }
    __syncthreads();

    float M = ml[0];
#pragma unroll
    for (int u = 1; u < 8; ++u) M = fmaxf(M, ml[u]);
    float lt = 0.f, wt = 0.f;
#pragma unroll
    for (int u = 0; u < 8; ++u) {
        float e = __expf(ml[u] - M);
        lt += e * ll[u];
        wt += e * wl[u * 512 + tid];
    }
    if (tid == 0) { pm[blk] = M; pl[blk] = lt; }
    pw[(size_t)blk * 512 + tid] = wt;
}

// ---------------------------------------------------------------------------
// Fused merge + W_ho GEMM + tanh + state/history writes.  2 batches/block.
// grid 64 x 512 thr; thread = one output h for both batches (shares W_ho row).
// ---------------------------------------------------------------------------
__global__ __launch_bounds__(512) void k_mergewho(
    const float* __restrict__ pm, const float* __restrict__ pl,
    const float* __restrict__ pw, const float* __restrict__ cat1,
    const float* __restrict__ W_ho, const float* __restrict__ b_ho,
    float* __restrict__ hbuf, float* __restrict__ hist_t)
{
    const int b0 = blockIdx.x * 2;
    const int h = threadIdx.x;
    __shared__ float catL[2][1024];

#pragma unroll
    for (int bb = 0; bb < 2; ++bb) {
        const int b = b0 + bb;
        float M = -INFINITY;
#pragma unroll
        for (int q = 0; q < 4; ++q) M = fmaxf(M, pm[4 * b + q]);
        float L = 0.f, wt = 0.f;
#pragma unroll
        for (int q = 0; q < 4; ++q) {
            float e = __expf(pm[4 * b + q] - M);
            L += e * pl[4 * b + q];
            wt += e * pw[(size_t)(4 * b + q) * 512 + h];
        }
        float wvv = wt / L;
        catL[bb][h] = wvv;
        catL[bb][512 + h] = cat1[(size_t)b * 1024 + 512 + h];
        hist_t[(size_t)b * 1024 + 512 + h] = wvv;
    }
    __syncthreads();

    float a0 = b_ho[h], a1 = a0;
    const float4* wrow = reinterpret_cast<const float4*>(W_ho + (size_t)h * 1024);
    for (int k4 = 0; k4 < 256; ++k4) {
        float4 w4 = wrow[k4];
        float4 c0 = *reinterpret_cast<const float4*>(&catL[0][k4 * 4]);
        float4 c1 = *reinterpret_cast<const float4*>(&catL[1][k4 * 4]);
        a0 = fmaf(w4.x, c0.x, a0); a0 = fmaf(w4.y, c0.y, a0);
        a0 = fmaf(w4.z, c0.z, a0); a0 = fmaf(w4.w, c0.w, a0);
        a1 = fmaf(w4.x, c1.x, a1); a1 = fmaf(w4.y, c1.y, a1);
        a1 = fmaf(w4.z, c1.z, a1); a1 = fmaf(w4.w, c1.w, a1);
    }
    float v0 = tanhf(a0), v1 = tanhf(a1);
    hbuf[(size_t)b0 * 512 + h] = v0;
    hbuf[(size_t)(b0 + 1) * 512 + h] = v1;
    hist_t[(size_t)b0 * 1024 + h] = v0;
    hist_t[(size_t)(b0 + 1) * 1024 + h] = v1;
}

__global__ __launch_bounds__(128) void k_argmax(const float* __restrict__ outp,
                                                float* __restrict__ preds)
{
    int row = blockIdx.x;
    int tid = threadIdx.x;
    float v = outp[(size_t)row * L_ + tid];
    int idx = tid;
#pragma unroll
    for (int off = 32; off > 0; off >>= 1) {
        float ov = __shfl_xor(v, off);
        int oi = __shfl_xor(idx, off);
        if (ov > v || (ov == v && oi < idx)) { v = ov; idx = oi; }
    }
    __shared__ float sv[2];
    __shared__ int si[2];
    if ((tid & 63) == 0) { sv[tid >> 6] = v; si[tid >> 6] = idx; }
    __syncthreads();
    if (tid == 0) {
        float v0 = sv[0], v1 = sv[1];
        int i0 = si[0], i1 = si[1];
        int r = (v1 > v0 || (v1 == v0 && i1 < i0)) ? i1 : i0;
        preds[row] = (float)r;
    }
}

__global__ void k_final(const float* __restrict__ hbuf, const float* __restrict__ cbuf,
                        float* __restrict__ hf, float* __restrict__ cf)
{
    int i = blockIdx.x * blockDim.x + threadIdx.x;
    hf[i] = hbuf[i];
    cf[i] = cbuf[i];
}

// ---------------------------------------------------------------------------
extern "C" void kernel_launch(void* const* d_in, const int* in_sizes, int n_in,
                              void* d_out, int out_size, void* d_ws, size_t ws_size,
                              hipStream_t stream)
{
    const float* dec_in  = (const float*)d_in[2];
    const float* h0      = (const float*)d_in[3];
    const float* c0      = (const float*)d_in[4];
    const float* context = (const float*)d_in[5];
    const int*   labels  = (const int*)d_in[6];
    const float* emb     = (const float*)d_in[8];
    const float* W_ih    = (const float*)d_in[9];
    const float* b_ih    = (const float*)d_in[10];
    const float* W_hh    = (const float*)d_in[11];
    const float* b_hh    = (const float*)d_in[12];
    const float* W_ho    = (const float*)d_in[13];
    const float* b_ho    = (const float*)d_in[14];
    const float* W_ain   = (const float*)d_in[15];
    const float* b_ain   = (const float*)d_in[16];
    const float* W_actx  = (const float*)d_in[17];
    const float* b_actx  = (const float*)d_in[18];
    const float* Vv      = (const float*)d_in[19];
    const float* W_out   = (const float*)d_in[20];
    const float* b_out   = (const float*)d_in[21];

    float* ws = (float*)d_ws;
    float* X     = ws; ws += (size_t)T_ * B_ * E_;          // 4.19M
    float* xproj = ws; ws += (size_t)T_ * B_ * G4H;         // 16.8M
    float* xout  = ws; ws += (size_t)T_ * B_ * L_;          // 1.05M
    float* ctx   = ws; ws += (size_t)B_ * S_ * H_;          // 67.1M fp32
    float* hist  = ws; ws += (size_t)T_ * B_ * 1024;        // 8.39M [hidden|weighted]
    float* Pg    = ws; ws += (size_t)4 * B_ * G4H;          // gate partials
    float* Pa    = ws; ws += (size_t)4 * B_ * H_;           // attn-in partials
    float* cbuf  = ws; ws += (size_t)B_ * H_;
    float* cat1  = ws; ws += (size_t)B_ * 1024;             // [- | h_lstm]
    float* hbuf  = ws; ws += (size_t)B_ * H_;
    float* pm    = ws; ws += 512;
    float* pl    = ws; ws += 512;
    float* pw    = ws; ws += (size_t)512 * 512;
    float* bsum  = ws; ws += G4H;

    float* out_logits = (float*)d_out;                      // [B,T,L]
    float* out_preds  = out_logits + (size_t)B_ * T_ * L_;
    float* out_hf     = out_preds + (size_t)B_ * T_;
    float* out_cf     = out_hf + (size_t)B_ * H_;

    // ---- precompute ----
    k_embed<<<2048, 256, 0, stream>>>(dec_in, labels, emb, X);
    k_init<<<256, 256, 0, stream>>>(h0, c0, b_ih, b_hh, hbuf, cbuf, bsum);
    gemm128<<<dim3(64, 16), 256, 0, stream>>>(X, E_, W_ih, E_, bsum, nullptr, 0,
                                              xproj, G4H, E_, 0, 0);
    gemm128<<<dim3(64, 1), 256, 0, stream>>>(X, E_, W_out + 1024, 1536, b_out, nullptr, 0,
                                             xout, L_, E_, 0, 0);
    // ctx = context @ W_attn_ctx^T + b  (fp32-accurate split-bf16 MFMA)
    gemm_ctx_split<<<dim3(4, 1024), 256, 0, stream>>>(context, W_actx, b_actx, ctx);

    // ---- sequential decode ----
    for (int t = 0; t < T_; ++t) {
        float* hist_t = hist + (size_t)t * B_ * 1024;
        gemm_stepk<<<dim3(32, 4), 256, 0, stream>>>(hbuf, H_, W_hh, H_, Pg, G4H, 128);
        k_lstm<<<256, 256, 0, stream>>>(Pg, xproj + (size_t)t * B_ * G4H, cbuf, cat1);
        gemm_stepk<<<dim3(8, 4), 256, 0, stream>>>(cat1 + 512, 1024, W_ain, H_, Pa, H_, 128);
        k_attn<<<512, 512, 0, stream>>>(ctx, Pa, b_ain, Vv, pm, pl, pw);
        k_mergewho<<<64, 512, 0, stream>>>(pm, pl, pw, cat1, W_ho, b_ho, hbuf, hist_t);
    }

    // ---- deferred logits GEMM + argmax ----
    gemm128<<<dim3(64, 1), 256, 0, stream>>>(hist, 1024, W_out, 1536, nullptr,
                                             xout, L_, out_logits, L_, 1024, 0, 1);
    k_argmax<<<B_ * T_, 128, 0, stream>>>(out_logits, out_preds);
    k_final<<<256, 256, 0, stream>>>(hbuf, cbuf, out_hf, out_cf);
}

// Round 5
// 8181.677 us; speedup vs baseline: 1.2569x; 1.2569x over previous
//
#include <hip/hip_runtime.h>
#include <hip/hip_bf16.h>
#include <math.h>

#define B_ 128
#define S_ 1024
#define H_ 512
#define E_ 512
#define T_ 64
#define L_ 128
#define G4H 2048  // 4*H

typedef __attribute__((ext_vector_type(8))) short bf16x8;
typedef __attribute__((ext_vector_type(4))) float f32x4;

__device__ inline float sigmoidf_(float x) { return 1.f / (1.f + expf(-x)); }
__device__ inline float fast_tanhf_(float x) {
    float e = __expf(2.f * x);
    return 1.f - 2.f / (e + 1.f);
}
__device__ inline unsigned f2bf1(float f) {
    unsigned u = __float_as_uint(f);
    return (u + 0x7fffu + ((u >> 16) & 1u)) >> 16;
}

// ---------------------------------------------------------------------------
// fp32-accurate GEMM via bf16 split MFMA (Markidis 3-product), validated R4.
// C[m,n] = act( A[m,:]·W[n,:] + bias[n] + Cinit[m,n] ), tile 128x128, 4 waves.
// M,N mult of 128, K mult of 32.  perm: row m=(t*B+b) -> C[(b*T+t)*ldc].
// ---------------------------------------------------------------------------
#define LDP 40  // 32 + 8 pad shorts per LDS row
__global__ __launch_bounds__(256) void gemm_split(
    const float* __restrict__ A, int lda,
    const float* __restrict__ W, int ldw,
    const float* __restrict__ bias,
    const float* __restrict__ Cinit, int ldci,
    float* __restrict__ C, int ldc,
    int K, int act, int perm)
{
    __shared__ unsigned short Ah[128 * LDP];
    __shared__ unsigned short Al[128 * LDP];
    __shared__ unsigned short Bh[128 * LDP];
    __shared__ unsigned short Bl[128 * LDP];
    const int n0 = blockIdx.x * 128;
    const int m0 = blockIdx.y * 128;
    const int t = threadIdx.x;
    const int lane = t & 63, wv = t >> 6;
    const int wr = wv >> 1, wc = wv & 1;
    const int row = t >> 1, koff = (t & 1) * 16;

    f32x4 acc[4][4] = {};

    for (int kt = 0; kt < K; kt += 32) {
        float av[16], wvv[16];
        {
            const float* ap = A + (size_t)(m0 + row) * lda + kt + koff;
            const float* wp = W + (size_t)(n0 + row) * ldw + kt + koff;
#pragma unroll
            for (int q = 0; q < 4; ++q) {
                *reinterpret_cast<float4*>(&av[q * 4]) = *reinterpret_cast<const float4*>(ap + q * 4);
                *reinterpret_cast<float4*>(&wvv[q * 4]) = *reinterpret_cast<const float4*>(wp + q * 4);
            }
        }
        unsigned short ah[16], al[16], bh[16], bl[16];
#pragma unroll
        for (int e = 0; e < 16; ++e) {
            unsigned ha = f2bf1(av[e]);
            float hf = __uint_as_float(ha << 16);
            ah[e] = (unsigned short)ha;
            al[e] = (unsigned short)f2bf1(av[e] - hf);
            unsigned hw = f2bf1(wvv[e]);
            float hwf = __uint_as_float(hw << 16);
            bh[e] = (unsigned short)hw;
            bl[e] = (unsigned short)f2bf1(wvv[e] - hwf);
        }
        __syncthreads();
        *reinterpret_cast<uint4*>(&Ah[row * LDP + koff])     = *reinterpret_cast<uint4*>(&ah[0]);
        *reinterpret_cast<uint4*>(&Ah[row * LDP + koff + 8]) = *reinterpret_cast<uint4*>(&ah[8]);
        *reinterpret_cast<uint4*>(&Al[row * LDP + koff])     = *reinterpret_cast<uint4*>(&al[0]);
        *reinterpret_cast<uint4*>(&Al[row * LDP + koff + 8]) = *reinterpret_cast<uint4*>(&al[8]);
        *reinterpret_cast<uint4*>(&Bh[row * LDP + koff])     = *reinterpret_cast<uint4*>(&bh[0]);
        *reinterpret_cast<uint4*>(&Bh[row * LDP + koff + 8]) = *reinterpret_cast<uint4*>(&bh[8]);
        *reinterpret_cast<uint4*>(&Bl[row * LDP + koff])     = *reinterpret_cast<uint4*>(&bl[0]);
        *reinterpret_cast<uint4*>(&Bl[row * LDP + koff + 8]) = *reinterpret_cast<uint4*>(&bl[8]);
        __syncthreads();

        bf16x8 fah[4], fal[4], fbh[4], fbl[4];
        const int kq = (lane >> 4) * 8;
#pragma unroll
        for (int i = 0; i < 4; ++i) {
            const int ar = wr * 64 + i * 16 + (lane & 15);
            const int br = wc * 64 + i * 16 + (lane & 15);
            fah[i] = *reinterpret_cast<const bf16x8*>(&Ah[ar * LDP + kq]);
            fal[i] = *reinterpret_cast<const bf16x8*>(&Al[ar * LDP + kq]);
            fbh[i] = *reinterpret_cast<const bf16x8*>(&Bh[br * LDP + kq]);
            fbl[i] = *reinterpret_cast<const bf16x8*>(&Bl[br * LDP + kq]);
        }
#pragma unroll
        for (int i = 0; i < 4; ++i)
#pragma unroll
            for (int j = 0; j < 4; ++j) {
                acc[i][j] = __builtin_amdgcn_mfma_f32_16x16x32_bf16(fah[i], fbh[j], acc[i][j], 0, 0, 0);
                acc[i][j] = __builtin_amdgcn_mfma_f32_16x16x32_bf16(fal[i], fbh[j], acc[i][j], 0, 0, 0);
                acc[i][j] = __builtin_amdgcn_mfma_f32_16x16x32_bf16(fah[i], fbl[j], acc[i][j], 0, 0, 0);
            }
    }

#pragma unroll
    for (int i = 0; i < 4; ++i)
#pragma unroll
        for (int j = 0; j < 4; ++j) {
            const int n = n0 + wc * 64 + j * 16 + (lane & 15);
            const float bs = bias ? bias[n] : 0.f;
#pragma unroll
            for (int r = 0; r < 4; ++r) {
                const int m = m0 + wr * 64 + i * 16 + (lane >> 4) * 4 + r;
                float v = acc[i][j][r] + bs;
                if (Cinit) v += Cinit[(size_t)m * ldci + n];
                if (act == 1) v = tanhf(v);
                size_t crow;
                if (perm) { int bb = m & 127, tt = m >> 7; crow = ((size_t)bb * T_ + tt) * ldc; }
                else crow = (size_t)m * ldc;
                C[crow + n] = v;
            }
        }
}

// ---------------------------------------------------------------------------
// Permute LSTM weights: row r' = 4h+g  <-  row g*512+h  (g = gate i/f/g/o)
// ---------------------------------------------------------------------------
__global__ __launch_bounds__(128) void k_perm(
    const float* __restrict__ W_ih, const float* __restrict__ W_hh,
    const float* __restrict__ b_ih, const float* __restrict__ b_hh,
    float* __restrict__ Wip, float* __restrict__ Whp, float* __restrict__ bp)
{
    int rp = blockIdx.x;              // 0..2047
    int h = rp >> 2, g = rp & 3;
    int src = g * 512 + h;
    int t = threadIdx.x;              // 128 thr, float4 each
    const float4* si = reinterpret_cast<const float4*>(W_ih + (size_t)src * 512);
    const float4* sh = reinterpret_cast<const float4*>(W_hh + (size_t)src * 512);
    float4* di = reinterpret_cast<float4*>(Wip + (size_t)rp * 512);
    float4* dh = reinterpret_cast<float4*>(Whp + (size_t)rp * 512);
    di[t] = si[t];
    dh[t] = sh[t];
    if (t == 0) bp[rp] = b_ih[src] + b_hh[src];
}

// ---------------------------------------------------------------------------
// Fused gates GEMM (permuted layout) + LSTM pointwise.
// grid (32 n-tiles, 4 m-tiles), 256 thr, tile 32(m) x 64(n'), K=512 serial.
// Thread (tx,ty): 2 rows x 4 cols where the 4 cols = gates i,f,g,o of one h.
// ---------------------------------------------------------------------------
__global__ __launch_bounds__(256) void k_gateslstm(
    const float* __restrict__ hbuf,      // [B,512]
    const float* __restrict__ Whp,       // [2048,512] permuted
    const float* __restrict__ xproj_t,   // [B,2048] permuted (incl. biases)
    float* __restrict__ cbuf,            // [B,512]
    float* __restrict__ hlstm)           // [B,512]
{
    __shared__ float As[16][32];
    __shared__ float Ws[16][64];
    const int n0 = blockIdx.x * 64;
    const int m0 = blockIdx.y * 32;
    const int t = threadIdx.x;
    const int tx = t & 15;      // 4 n'-cols = one h
    const int ty = t >> 4;      // 2 m-rows
    const int alr = t >> 3, alk = (t & 7) * 2;   // A: 32 rows x 16 k, float2
    const int wlr = t >> 2, wlk = (t & 3) * 4;   // W: 64 rows x 16 k, float4

    float acc[2][4] = {};

    for (int k0 = 0; k0 < 512; k0 += 16) {
        float2 a2 = *reinterpret_cast<const float2*>(hbuf + (size_t)(m0 + alr) * 512 + k0 + alk);
        float4 w4 = *reinterpret_cast<const float4*>(Whp + (size_t)(n0 + wlr) * 512 + k0 + wlk);
        __syncthreads();
        As[alk + 0][alr] = a2.x; As[alk + 1][alr] = a2.y;
        Ws[wlk + 0][wlr] = w4.x; Ws[wlk + 1][wlr] = w4.y;
        Ws[wlk + 2][wlr] = w4.z; Ws[wlk + 3][wlr] = w4.w;
        __syncthreads();
#pragma unroll
        for (int kk = 0; kk < 16; ++kk) {
            float a[2], b[4];
            a[0] = As[kk][ty * 2]; a[1] = As[kk][ty * 2 + 1];
#pragma unroll
            for (int j = 0; j < 4; ++j) b[j] = Ws[kk][tx * 4 + j];
#pragma unroll
            for (int i = 0; i < 2; ++i)
#pragma unroll
                for (int j = 0; j < 4; ++j) acc[i][j] = fmaf(a[i], b[j], acc[i][j]);
        }
    }

    const int h = (n0 >> 2) + tx;
#pragma unroll
    for (int i = 0; i < 2; ++i) {
        const int b = m0 + ty * 2 + i;
        float4 xp = *reinterpret_cast<const float4*>(xproj_t + (size_t)b * G4H + n0 + tx * 4);
        float ig = sigmoidf_(acc[i][0] + xp.x);
        float fg = sigmoidf_(acc[i][1] + xp.y);
        float gg = tanhf(acc[i][2] + xp.z);
        float og = sigmoidf_(acc[i][3] + xp.w);
        float c = fg * cbuf[(size_t)b * 512 + h] + ig * gg;
        cbuf[(size_t)b * 512 + h] = c;
        hlstm[(size_t)b * 512 + h] = og * tanhf(c);
    }
}

// ---------------------------------------------------------------------------
// Small-M split-K GEMM (proven R2): partials P[(ks*128+m)*N + n]
// ---------------------------------------------------------------------------
__global__ __launch_bounds__(256) void gemm_stepk(
    const float* __restrict__ A, int lda,
    const float* __restrict__ W, int ldw,
    float* __restrict__ P, int N, int Kc)
{
    __shared__ float As[16][128];
    __shared__ float Ws[16][64];
    const int n0 = blockIdx.x * 64;
    const int k0 = blockIdx.y * Kc;
    const int t = threadIdx.x;
    const int tx = t & 15;
    const int ty = t >> 4;
    const int ar = t >> 1, akq = (t & 1) * 8;
    const int wr = t >> 2, wkq = (t & 3) * 4;

    float acc[8][4] = {};

    for (int kb = 0; kb < Kc; kb += 16) {
        float4 a0 = *reinterpret_cast<const float4*>(A + (size_t)ar * lda + k0 + kb + akq);
        float4 a1 = *reinterpret_cast<const float4*>(A + (size_t)ar * lda + k0 + kb + akq + 4);
        float4 w0 = *reinterpret_cast<const float4*>(W + (size_t)(n0 + wr) * ldw + k0 + kb + wkq);
        __syncthreads();
        As[akq + 0][ar] = a0.x; As[akq + 1][ar] = a0.y; As[akq + 2][ar] = a0.z; As[akq + 3][ar] = a0.w;
        As[akq + 4][ar] = a1.x; As[akq + 5][ar] = a1.y; As[akq + 6][ar] = a1.z; As[akq + 7][ar] = a1.w;
        Ws[wkq + 0][wr] = w0.x; Ws[wkq + 1][wr] = w0.y; Ws[wkq + 2][wr] = w0.z; Ws[wkq + 3][wr] = w0.w;
        __syncthreads();
#pragma unroll
        for (int kk = 0; kk < 16; ++kk) {
            float a[8], b[4];
#pragma unroll
            for (int i = 0; i < 8; ++i) a[i] = As[kk][ty * 8 + i];
#pragma unroll
            for (int j = 0; j < 4; ++j) b[j] = Ws[kk][tx * 4 + j];
#pragma unroll
            for (int i = 0; i < 8; ++i)
#pragma unroll
                for (int j = 0; j < 4; ++j) acc[i][j] = fmaf(a[i], b[j], acc[i][j]);
        }
    }

#pragma unroll
    for (int i = 0; i < 8; ++i) {
        const int m = ty * 8 + i;
#pragma unroll
        for (int j = 0; j < 4; ++j)
            P[((size_t)blockIdx.y * 128 + m) * N + n0 + tx * 4 + j] = acc[i][j];
    }
}

// ---------------------------------------------------------------------------
// W_ho GEMM with fused softmax-merge A-staging.
// A(virtual)[b][k] = weighted[b][k] (k<512, merged from pw/pm/pl) or
//                    hlstm[b][k-512].  Split-K 8x128, tile 128x64.
// Blocks (x==0, y<4) also write weighted -> hist_t[b][512+k].
// ---------------------------------------------------------------------------
__global__ __launch_bounds__(256) void k_who(
    const float* __restrict__ pm, const float* __restrict__ pl,
    const float* __restrict__ pw, const float* __restrict__ hlstm,
    const float* __restrict__ W_ho,
    float* __restrict__ P, float* __restrict__ hist_t)
{
    __shared__ float As[16][128];
    __shared__ float Ws[16][64];
    __shared__ float eql[128][4];
    const int n0 = blockIdx.x * 64;
    const int k0 = blockIdx.y * 128;
    const int t = threadIdx.x;
    const int tx = t & 15;
    const int ty = t >> 4;
    const int ar = t >> 1, akq = (t & 1) * 8;
    const int wr = t >> 2, wkq = (t & 3) * 4;
    const bool merge_side = (k0 < 512);
    const bool writer = (blockIdx.x == 0) && merge_side;

    if (merge_side && t < 128) {
        float m0 = pm[4 * t], m1 = pm[4 * t + 1], m2 = pm[4 * t + 2], m3 = pm[4 * t + 3];
        float M = fmaxf(fmaxf(m0, m1), fmaxf(m2, m3));
        float e0 = __expf(m0 - M), e1 = __expf(m1 - M), e2 = __expf(m2 - M), e3 = __expf(m3 - M);
        float Lt = e0 * pl[4 * t] + e1 * pl[4 * t + 1] + e2 * pl[4 * t + 2] + e3 * pl[4 * t + 3];
        float inv = 1.f / Lt;
        eql[t][0] = e0 * inv; eql[t][1] = e1 * inv; eql[t][2] = e2 * inv; eql[t][3] = e3 * inv;
    }
    __syncthreads();

    float acc[8][4] = {};

    for (int kb = 0; kb < 128; kb += 16) {
        float av[8];
        const int kg = k0 + kb + akq;        // global k for this thread's 8 elems
        if (merge_side) {
            float4 p0a = *reinterpret_cast<const float4*>(pw + ((size_t)(4 * ar + 0) * 512) + kg);
            float4 p0b = *reinterpret_cast<const float4*>(pw + ((size_t)(4 * ar + 0) * 512) + kg + 4);
            float4 p1a = *reinterpret_cast<const float4*>(pw + ((size_t)(4 * ar + 1) * 512) + kg);
            float4 p1b = *reinterpret_cast<const float4*>(pw + ((size_t)(4 * ar + 1) * 512) + kg + 4);
            float4 p2a = *reinterpret_cast<const float4*>(pw + ((size_t)(4 * ar + 2) * 512) + kg);
            float4 p2b = *reinterpret_cast<const float4*>(pw + ((size_t)(4 * ar + 2) * 512) + kg + 4);
            float4 p3a = *reinterpret_cast<const float4*>(pw + ((size_t)(4 * ar + 3) * 512) + kg);
            float4 p3b = *reinterpret_cast<const float4*>(pw + ((size_t)(4 * ar + 3) * 512) + kg + 4);
            float q0 = eql[ar][0], q1 = eql[ar][1], q2 = eql[ar][2], q3 = eql[ar][3];
            av[0] = q0 * p0a.x + q1 * p1a.x + q2 * p2a.x + q3 * p3a.x;
            av[1] = q0 * p0a.y + q1 * p1a.y + q2 * p2a.y + q3 * p3a.y;
            av[2] = q0 * p0a.z + q1 * p1a.z + q2 * p2a.z + q3 * p3a.z;
            av[3] = q0 * p0a.w + q1 * p1a.w + q2 * p2a.w + q3 * p3a.w;
            av[4] = q0 * p0b.x + q1 * p1b.x + q2 * p2b.x + q3 * p3b.x;
            av[5] = q0 * p0b.y + q1 * p1b.y + q2 * p2b.y + q3 * p3b.y;
            av[6] = q0 * p0b.z + q1 * p1b.z + q2 * p2b.z + q3 * p3b.z;
            av[7] = q0 * p0b.w + q1 * p1b.w + q2 * p2b.w + q3 * p3b.w;
            if (writer) {
                *reinterpret_cast<float4*>(hist_t + (size_t)ar * 1024 + 512 + kg) = *reinterpret_cast<float4*>(&av[0]);
                *reinterpret_cast<float4*>(hist_t + (size_t)ar * 1024 + 512 + kg + 4) = *reinterpret_cast<float4*>(&av[4]);
            }
        } else {
            *reinterpret_cast<float4*>(&av[0]) = *reinterpret_cast<const float4*>(hlstm + (size_t)ar * 512 + kg - 512);
            *reinterpret_cast<float4*>(&av[4]) = *reinterpret_cast<const float4*>(hlstm + (size_t)ar * 512 + kg - 512 + 4);
        }
        float4 w0 = *reinterpret_cast<const float4*>(W_ho + (size_t)(n0 + wr) * 1024 + k0 + kb + wkq);
        __syncthreads();
        As[akq + 0][ar] = av[0]; As[akq + 1][ar] = av[1]; As[akq + 2][ar] = av[2]; As[akq + 3][ar] = av[3];
        As[akq + 4][ar] = av[4]; As[akq + 5][ar] = av[5]; As[akq + 6][ar] = av[6]; As[akq + 7][ar] = av[7];
        Ws[wkq + 0][wr] = w0.x; Ws[wkq + 1][wr] = w0.y; Ws[wkq + 2][wr] = w0.z; Ws[wkq + 3][wr] = w0.w;
        __syncthreads();
#pragma unroll
        for (int kk = 0; kk < 16; ++kk) {
            float a[8], b[4];
#pragma unroll
            for (int i = 0; i < 8; ++i) a[i] = As[kk][ty * 8 + i];
#pragma unroll
            for (int j = 0; j < 4; ++j) b[j] = Ws[kk][tx * 4 + j];
#pragma unroll
            for (int i = 0; i < 8; ++i)
#pragma unroll
                for (int j = 0; j < 4; ++j) acc[i][j] = fmaf(a[i], b[j], acc[i][j]);
        }
    }

#pragma unroll
    for (int i = 0; i < 8; ++i) {
        const int m = ty * 8 + i;
#pragma unroll
        for (int j = 0; j < 4; ++j)
            P[((size_t)blockIdx.y * 128 + m) * 512 + n0 + tx * 4 + j] = acc[i][j];
    }
}

// ---------------------------------------------------------------------------
__global__ void k_embed(const float* __restrict__ dec_in, const int* __restrict__ labels,
                        const float* __restrict__ emb, float* __restrict__ X)
{
    size_t total = (size_t)T_ * B_ * E_;
    for (size_t i = (size_t)blockIdx.x * blockDim.x + threadIdx.x; i < total;
         i += (size_t)gridDim.x * blockDim.x) {
        int e = (int)(i % E_);
        int b = (int)((i / E_) % B_);
        int t = (int)(i / ((size_t)E_ * B_));
        float v;
        if (t == 0) v = dec_in[b * E_ + e];
        else {
            int lab = labels[b * T_ + (t - 1)];
            v = emb[(size_t)lab * E_ + e];
        }
        X[i] = v;
    }
}

__global__ void k_init(const float* __restrict__ h0, const float* __restrict__ c0,
                       float* __restrict__ hbuf, float* __restrict__ cbuf)
{
    int i = blockIdx.x * blockDim.x + threadIdx.x;
    hbuf[i] = h0[i];
    cbuf[i] = c0[i];
}

// ---------------------------------------------------------------------------
// Attention (fp32 ctx, proven R2): block (b, quarter) = 256 s-values.
// ---------------------------------------------------------------------------
__global__ __launch_bounds__(512) void k_attn(const float* __restrict__ ctx,
    const float* __restrict__ Pa, const float* __restrict__ b_ain,
    const float* __restrict__ Vv,
    float* __restrict__ pm, float* __restrict__ pl, float* __restrict__ pw)
{
    int blk = blockIdx.x;
    int b = blk >> 2, q = blk & 3;
    int tid = threadIdx.x, lane = tid & 63, wv = tid >> 6;

    __shared__ float inp_sh[512];
    inp_sh[tid] = Pa[(size_t)b * 512 + tid]
                + Pa[(size_t)(128 + b) * 512 + tid]
                + Pa[(size_t)(256 + b) * 512 + tid]
                + Pa[(size_t)(384 + b) * 512 + tid]
                + b_ain[tid];
    __syncthreads();

    float inpr[8], vr[8];
    {
        const float4* v4 = reinterpret_cast<const float4*>(Vv) + lane * 2;
        *(float4*)&vr[0] = v4[0];   *(float4*)&vr[4] = v4[1];
#pragma unroll
        for (int k = 0; k < 8; ++k) inpr[k] = inp_sh[lane * 8 + k];
    }
    const float* cbase = ctx + (size_t)b * S_ * H_ + (size_t)(q * 256) * H_;

    float m = -INFINITY, l = 0.f, w[8] = {};
    for (int si = 0; si < 32; ++si) {
        int s = wv * 32 + si;
        const float4* cp = reinterpret_cast<const float4*>(cbase + (size_t)s * H_) + lane * 2;
        float c8[8];
        *(float4*)&c8[0] = cp[0]; *(float4*)&c8[4] = cp[1];
        float t = 0.f;
#pragma unroll
        for (int k = 0; k < 8; ++k) t = fmaf(fast_tanhf_(inpr[k] + c8[k]), vr[k], t);
#pragma unroll
        for (int off = 32; off > 0; off >>= 1) t += __shfl_xor(t, off);
        float mn = fmaxf(m, t);
        float sc = __expf(m - mn);
        float p  = __expf(t - mn);
        l = l * sc + p;
#pragma unroll
        for (int k = 0; k < 8; ++k) w[k] = w[k] * sc + p * c8[k];
        m = mn;
    }

    __shared__ float wl[8 * 512];
    __shared__ float ml[8], ll[8];
#pragma unroll
    for (int k = 0; k < 8; ++k) wl[wv * 512 + lane * 8 + k] = w[k];
    if (lane == 0) { ml[wv] = m; ll[wv] = l; }
    __syncthreads();

    float M = ml[0];
#pragma unroll
    for (int u = 1; u < 8; ++u) M = fmaxf(M, ml[u]);
    float lt = 0.f, wt = 0.f;
#pragma unroll
    for (int u = 0; u < 8; ++u) {
        float e = __expf(ml[u] - M);
        lt += e * ll[u];
        wt += e * wl[u * 512 + tid];
    }
    if (tid == 0) { pm[blk] = M; pl[blk] = lt; }
    pw[(size_t)blk * 512 + tid] = wt;
}

// finalize W_ho: sum 8 partials + bias, tanh -> hbuf and hist_t[:,0:512]
__global__ __launch_bounds__(256) void k_whofin(const float* __restrict__ Po,
    const float* __restrict__ b_ho, float* __restrict__ hbuf, float* __restrict__ hist_t)
{
    int i = blockIdx.x * blockDim.x + threadIdx.x;   // B*H
    int b = i >> 9, h = i & 511;
    float v = b_ho[h];
#pragma unroll
    for (int ks = 0; ks < 8; ++ks) v += Po[((size_t)ks * 128 + b) * 512 + h];
    v = tanhf(v);
    hbuf[i] = v;
    hist_t[(size_t)b * 1024 + h] = v;
}

__global__ __launch_bounds__(128) void k_argmax(const float* __restrict__ outp,
                                                float* __restrict__ preds)
{
    int row = blockIdx.x;
    int tid = threadIdx.x;
    float v = outp[(size_t)row * L_ + tid];
    int idx = tid;
#pragma unroll
    for (int off = 32; off > 0; off >>= 1) {
        float ov = __shfl_xor(v, off);
        int oi = __shfl_xor(idx, off);
        if (ov > v || (ov == v && oi < idx)) { v = ov; idx = oi; }
    }
    __shared__ float sv[2];
    __shared__ int si[2];
    if ((tid & 63) == 0) { sv[tid >> 6] = v; si[tid >> 6] = idx; }
    __syncthreads();
    if (tid == 0) {
        float v0 = sv[0], v1 = sv[1];
        int i0 = si[0], i1 = si[1];
        int r = (v1 > v0 || (v1 == v0 && i1 < i0)) ? i1 : i0;
        preds[row] = (float)r;
    }
}

__global__ void k_final(const float* __restrict__ hbuf, const float* __restrict__ cbuf,
                        float* __restrict__ hf, float* __restrict__ cf)
{
    int i = blockIdx.x * blockDim.x + threadIdx.x;
    hf[i] = hbuf[i];
    cf[i] = cbuf[i];
}

// ---------------------------------------------------------------------------
extern "C" void kernel_launch(void* const* d_in, const int* in_sizes, int n_in,
                              void* d_out, int out_size, void* d_ws, size_t ws_size,
                              hipStream_t stream)
{
    const float* dec_in  = (const float*)d_in[2];
    const float* h0      = (const float*)d_in[3];
    const float* c0      = (const float*)d_in[4];
    const float* context = (const float*)d_in[5];
    const int*   labels  = (const int*)d_in[6];
    const float* emb     = (const float*)d_in[8];
    const float* W_ih    = (const float*)d_in[9];
    const float* b_ih    = (const float*)d_in[10];
    const float* W_hh    = (const float*)d_in[11];
    const float* b_hh    = (const float*)d_in[12];
    const float* W_ho    = (const float*)d_in[13];
    const float* b_ho    = (const float*)d_in[14];
    const float* W_ain   = (const float*)d_in[15];
    const float* b_ain   = (const float*)d_in[16];
    const float* W_actx  = (const float*)d_in[17];
    const float* b_actx  = (const float*)d_in[18];
    const float* Vv      = (const float*)d_in[19];
    const float* W_out   = (const float*)d_in[20];
    const float* b_out   = (const float*)d_in[21];

    float* ws = (float*)d_ws;
    float* X     = ws; ws += (size_t)T_ * B_ * E_;          // 4.19M
    float* xproj = ws; ws += (size_t)T_ * B_ * G4H;         // 16.8M (permuted cols)
    float* xout  = ws; ws += (size_t)T_ * B_ * L_;          // 1.05M
    float* ctx   = ws; ws += (size_t)B_ * S_ * H_;          // 67.1M fp32
    float* hist  = ws; ws += (size_t)T_ * B_ * 1024;        // 8.39M [hidden|weighted]
    float* Wip   = ws; ws += (size_t)G4H * 512;             // 1.05M permuted W_ih
    float* Whp   = ws; ws += (size_t)G4H * 512;             // 1.05M permuted W_hh
    float* bp    = ws; ws += G4H;
    float* Pa    = ws; ws += (size_t)4 * B_ * H_;           // attn-in partials
    float* Po    = ws; ws += (size_t)8 * B_ * H_;           // who partials
    float* cbuf  = ws; ws += (size_t)B_ * H_;
    float* hbuf  = ws; ws += (size_t)B_ * H_;
    float* hlstm = ws; ws += (size_t)B_ * H_;
    float* pm    = ws; ws += 512;
    float* pl    = ws; ws += 512;
    float* pw    = ws; ws += (size_t)512 * 512;

    float* out_logits = (float*)d_out;                      // [B,T,L]
    float* out_preds  = out_logits + (size_t)B_ * T_ * L_;
    float* out_hf     = out_preds + (size_t)B_ * T_;
    float* out_cf     = out_hf + (size_t)B_ * H_;

    // ---- precompute ----
    k_embed<<<2048, 256, 0, stream>>>(dec_in, labels, emb, X);
    k_init<<<256, 256, 0, stream>>>(h0, c0, hbuf, cbuf);
    k_perm<<<G4H, 128, 0, stream>>>(W_ih, W_hh, b_ih, b_hh, Wip, Whp, bp);
    // xproj (permuted) = X @ Wip^T + bp
    gemm_split<<<dim3(16, 64), 256, 0, stream>>>(X, E_, Wip, E_, bp, nullptr, 0,
                                                 xproj, G4H, E_, 0, 0);
    // xout = X @ W_out[:,1024:1536]^T + b_out
    gemm_split<<<dim3(1, 64), 256, 0, stream>>>(X, E_, W_out + 1024, 1536, b_out, nullptr, 0,
                                                xout, L_, E_, 0, 0);
    // ctx = context @ W_attn_ctx^T + b_attn_ctx
    gemm_split<<<dim3(4, 1024), 256, 0, stream>>>(context, H_, W_actx, H_, b_actx, nullptr, 0,
                                                  ctx, H_, H_, 0, 0);

    // ---- sequential decode: 5 kernels/step ----
    for (int t = 0; t < T_; ++t) {
        float* hist_t = hist + (size_t)t * B_ * 1024;
        k_gateslstm<<<dim3(32, 4), 256, 0, stream>>>(hbuf, Whp,
                                                     xproj + (size_t)t * B_ * G4H,
                                                     cbuf, hlstm);
        gemm_stepk<<<dim3(8, 4), 256, 0, stream>>>(hlstm, H_, W_ain, H_, Pa, H_, 128);
        k_attn<<<512, 512, 0, stream>>>(ctx, Pa, b_ain, Vv, pm, pl, pw);
        k_who<<<dim3(8, 8), 256, 0, stream>>>(pm, pl, pw, hlstm, W_ho, Po, hist_t);
        k_whofin<<<256, 256, 0, stream>>>(Po, b_ho, hbuf, hist_t);
    }

    // ---- deferred logits GEMM + argmax ----
    gemm_split<<<dim3(1, 64), 256, 0, stream>>>(hist, 1024, W_out, 1536, nullptr,
                                                xout, L_, out_logits, L_, 1024, 0, 1);
    k_argmax<<<B_ * T_, 128, 0, stream>>>(out_logits, out_preds);
    k_final<<<256, 256, 0, stream>>>(hbuf, cbuf, out_hf, out_cf);
}

// Round 6
// 7469.922 us; speedup vs baseline: 1.3767x; 1.0953x over previous
//
#include <hip/hip_runtime.h>
#include <hip/hip_bf16.h>
#include <math.h>

#define B_ 128
#define S_ 1024
#define H_ 512
#define E_ 512
#define T_ 64
#define L_ 128
#define G4H 2048  // 4*H
#define QS 8      // attention s-splits

typedef __attribute__((ext_vector_type(8))) short bf16x8;
typedef __attribute__((ext_vector_type(4))) float f32x4;

__device__ inline float sigmoidf_(float x) { return 1.f / (1.f + expf(-x)); }
__device__ inline float fast_tanhf_(float x) {
    float e = __expf(2.f * x);
    return 1.f - 2.f / (e + 1.f);
}
__device__ inline unsigned f2bf1(float f) {
    unsigned u = __float_as_uint(f);
    return (u + 0x7fffu + ((u >> 16) & 1u)) >> 16;
}

// ---------------------------------------------------------------------------
// fp32-accurate GEMM via bf16 split MFMA (Markidis 3-product), validated R4.
// Now with register-prefetch of the next K-tile.
// ---------------------------------------------------------------------------
#define LDP 40  // 32 + 8 pad shorts per LDS row
__global__ __launch_bounds__(256) void gemm_split(
    const float* __restrict__ A, int lda,
    const float* __restrict__ W, int ldw,
    const float* __restrict__ bias,
    const float* __restrict__ Cinit, int ldci,
    float* __restrict__ C, int ldc,
    int K, int act, int perm)
{
    __shared__ unsigned short Ah[128 * LDP];
    __shared__ unsigned short Al[128 * LDP];
    __shared__ unsigned short Bh[128 * LDP];
    __shared__ unsigned short Bl[128 * LDP];
    const int n0 = blockIdx.x * 128;
    const int m0 = blockIdx.y * 128;
    const int t = threadIdx.x;
    const int lane = t & 63, wv = t >> 6;
    const int wr = wv >> 1, wc = wv & 1;
    const int row = t >> 1, koff = (t & 1) * 16;

    f32x4 acc[4][4] = {};

    float av[16], wvv[16];
    {
        const float* ap = A + (size_t)(m0 + row) * lda + koff;
        const float* wp = W + (size_t)(n0 + row) * ldw + koff;
#pragma unroll
        for (int q = 0; q < 4; ++q) {
            *reinterpret_cast<float4*>(&av[q * 4]) = *reinterpret_cast<const float4*>(ap + q * 4);
            *reinterpret_cast<float4*>(&wvv[q * 4]) = *reinterpret_cast<const float4*>(wp + q * 4);
        }
    }

    for (int kt = 0; kt < K; kt += 32) {
        unsigned short ah[16], al[16], bh[16], bl[16];
#pragma unroll
        for (int e = 0; e < 16; ++e) {
            unsigned ha = f2bf1(av[e]);
            float hf = __uint_as_float(ha << 16);
            ah[e] = (unsigned short)ha;
            al[e] = (unsigned short)f2bf1(av[e] - hf);
            unsigned hw = f2bf1(wvv[e]);
            float hwf = __uint_as_float(hw << 16);
            bh[e] = (unsigned short)hw;
            bl[e] = (unsigned short)f2bf1(wvv[e] - hwf);
        }
        __syncthreads();
        *reinterpret_cast<uint4*>(&Ah[row * LDP + koff])     = *reinterpret_cast<uint4*>(&ah[0]);
        *reinterpret_cast<uint4*>(&Ah[row * LDP + koff + 8]) = *reinterpret_cast<uint4*>(&ah[8]);
        *reinterpret_cast<uint4*>(&Al[row * LDP + koff])     = *reinterpret_cast<uint4*>(&al[0]);
        *reinterpret_cast<uint4*>(&Al[row * LDP + koff + 8]) = *reinterpret_cast<uint4*>(&al[8]);
        *reinterpret_cast<uint4*>(&Bh[row * LDP + koff])     = *reinterpret_cast<uint4*>(&bh[0]);
        *reinterpret_cast<uint4*>(&Bh[row * LDP + koff + 8]) = *reinterpret_cast<uint4*>(&bh[8]);
        *reinterpret_cast<uint4*>(&Bl[row * LDP + koff])     = *reinterpret_cast<uint4*>(&bl[0]);
        *reinterpret_cast<uint4*>(&Bl[row * LDP + koff + 8]) = *reinterpret_cast<uint4*>(&bl[8]);
        __syncthreads();

        if (kt + 32 < K) {
            const float* ap = A + (size_t)(m0 + row) * lda + kt + 32 + koff;
            const float* wp = W + (size_t)(n0 + row) * ldw + kt + 32 + koff;
#pragma unroll
            for (int q = 0; q < 4; ++q) {
                *reinterpret_cast<float4*>(&av[q * 4]) = *reinterpret_cast<const float4*>(ap + q * 4);
                *reinterpret_cast<float4*>(&wvv[q * 4]) = *reinterpret_cast<const float4*>(wp + q * 4);
            }
        }

        bf16x8 fah[4], fal[4], fbh[4], fbl[4];
        const int kq = (lane >> 4) * 8;
#pragma unroll
        for (int i = 0; i < 4; ++i) {
            const int ar = wr * 64 + i * 16 + (lane & 15);
            const int br = wc * 64 + i * 16 + (lane & 15);
            fah[i] = *reinterpret_cast<const bf16x8*>(&Ah[ar * LDP + kq]);
            fal[i] = *reinterpret_cast<const bf16x8*>(&Al[ar * LDP + kq]);
            fbh[i] = *reinterpret_cast<const bf16x8*>(&Bh[br * LDP + kq]);
            fbl[i] = *reinterpret_cast<const bf16x8*>(&Bl[br * LDP + kq]);
        }
#pragma unroll
        for (int i = 0; i < 4; ++i)
#pragma unroll
            for (int j = 0; j < 4; ++j) {
                acc[i][j] = __builtin_amdgcn_mfma_f32_16x16x32_bf16(fah[i], fbh[j], acc[i][j], 0, 0, 0);
                acc[i][j] = __builtin_amdgcn_mfma_f32_16x16x32_bf16(fal[i], fbh[j], acc[i][j], 0, 0, 0);
                acc[i][j] = __builtin_amdgcn_mfma_f32_16x16x32_bf16(fah[i], fbl[j], acc[i][j], 0, 0, 0);
            }
    }

#pragma unroll
    for (int i = 0; i < 4; ++i)
#pragma unroll
        for (int j = 0; j < 4; ++j) {
            const int n = n0 + wc * 64 + j * 16 + (lane & 15);
            const float bs = bias ? bias[n] : 0.f;
#pragma unroll
            for (int r = 0; r < 4; ++r) {
                const int m = m0 + wr * 64 + i * 16 + (lane >> 4) * 4 + r;
                float v = acc[i][j][r] + bs;
                if (Cinit) v += Cinit[(size_t)m * ldci + n];
                if (act == 1) v = tanhf(v);
                size_t crow;
                if (perm) { int bb = m & 127, tt = m >> 7; crow = ((size_t)bb * T_ + tt) * ldc; }
                else crow = (size_t)m * ldc;
                C[crow + n] = v;
            }
        }
}

// ---------------------------------------------------------------------------
// Permute LSTM weights: row r' = 4h+g  <-  row g*512+h
// ---------------------------------------------------------------------------
__global__ __launch_bounds__(128) void k_perm(
    const float* __restrict__ W_ih, const float* __restrict__ W_hh,
    const float* __restrict__ b_ih, const float* __restrict__ b_hh,
    float* __restrict__ Wip, float* __restrict__ Whp, float* __restrict__ bp)
{
    int rp = blockIdx.x;
    int h = rp >> 2, g = rp & 3;
    int src = g * 512 + h;
    int t = threadIdx.x;
    const float4* si = reinterpret_cast<const float4*>(W_ih + (size_t)src * 512);
    const float4* sh = reinterpret_cast<const float4*>(W_hh + (size_t)src * 512);
    float4* di = reinterpret_cast<float4*>(Wip + (size_t)rp * 512);
    float4* dh = reinterpret_cast<float4*>(Whp + (size_t)rp * 512);
    di[t] = si[t];
    dh[t] = sh[t];
    if (t == 0) bp[rp] = b_ih[src] + b_hh[src];
}

// ---------------------------------------------------------------------------
// Fused gates GEMM (permuted) + LSTM pointwise, register-prefetched.
// ---------------------------------------------------------------------------
__global__ __launch_bounds__(256) void k_gateslstm(
    const float* __restrict__ hbuf,
    const float* __restrict__ Whp,
    const float* __restrict__ xproj_t,
    float* __restrict__ cbuf,
    float* __restrict__ hlstm)
{
    __shared__ float As[16][32];
    __shared__ float Ws[16][64];
    const int n0 = blockIdx.x * 64;
    const int m0 = blockIdx.y * 32;
    const int t = threadIdx.x;
    const int tx = t & 15;
    const int ty = t >> 4;
    const int alr = t >> 3, alk = (t & 7) * 2;
    const int wlr = t >> 2, wlk = (t & 3) * 4;

    float acc[2][4] = {};

    float2 pa = *reinterpret_cast<const float2*>(hbuf + (size_t)(m0 + alr) * 512 + alk);
    float4 pv = *reinterpret_cast<const float4*>(Whp + (size_t)(n0 + wlr) * 512 + wlk);

    for (int k0 = 0; k0 < 512; k0 += 16) {
        __syncthreads();
        As[alk + 0][alr] = pa.x; As[alk + 1][alr] = pa.y;
        Ws[wlk + 0][wlr] = pv.x; Ws[wlk + 1][wlr] = pv.y;
        Ws[wlk + 2][wlr] = pv.z; Ws[wlk + 3][wlr] = pv.w;
        __syncthreads();
        if (k0 + 16 < 512) {
            pa = *reinterpret_cast<const float2*>(hbuf + (size_t)(m0 + alr) * 512 + k0 + 16 + alk);
            pv = *reinterpret_cast<const float4*>(Whp + (size_t)(n0 + wlr) * 512 + k0 + 16 + wlk);
        }
#pragma unroll
        for (int kk = 0; kk < 16; ++kk) {
            float a[2], b[4];
            a[0] = As[kk][ty * 2]; a[1] = As[kk][ty * 2 + 1];
#pragma unroll
            for (int j = 0; j < 4; ++j) b[j] = Ws[kk][tx * 4 + j];
#pragma unroll
            for (int i = 0; i < 2; ++i)
#pragma unroll
                for (int j = 0; j < 4; ++j) acc[i][j] = fmaf(a[i], b[j], acc[i][j]);
        }
    }

    const int h = (n0 >> 2) + tx;
#pragma unroll
    for (int i = 0; i < 2; ++i) {
        const int b = m0 + ty * 2 + i;
        float4 xp = *reinterpret_cast<const float4*>(xproj_t + (size_t)b * G4H + n0 + tx * 4);
        float ig = sigmoidf_(acc[i][0] + xp.x);
        float fg = sigmoidf_(acc[i][1] + xp.y);
        float gg = tanhf(acc[i][2] + xp.z);
        float og = sigmoidf_(acc[i][3] + xp.w);
        float c = fg * cbuf[(size_t)b * 512 + h] + ig * gg;
        cbuf[(size_t)b * 512 + h] = c;
        hlstm[(size_t)b * 512 + h] = og * tanhf(c);
    }
}

// ---------------------------------------------------------------------------
// Small-M split-K GEMM, register-prefetched.
// ---------------------------------------------------------------------------
__global__ __launch_bounds__(256) void gemm_stepk(
    const float* __restrict__ A, int lda,
    const float* __restrict__ W, int ldw,
    float* __restrict__ P, int N, int Kc)
{
    __shared__ float As[16][128];
    __shared__ float Ws[16][64];
    const int n0 = blockIdx.x * 64;
    const int k0 = blockIdx.y * Kc;
    const int t = threadIdx.x;
    const int tx = t & 15;
    const int ty = t >> 4;
    const int ar = t >> 1, akq = (t & 1) * 8;
    const int wr = t >> 2, wkq = (t & 3) * 4;

    float acc[8][4] = {};

    float4 a0 = *reinterpret_cast<const float4*>(A + (size_t)ar * lda + k0 + akq);
    float4 a1 = *reinterpret_cast<const float4*>(A + (size_t)ar * lda + k0 + akq + 4);
    float4 w0 = *reinterpret_cast<const float4*>(W + (size_t)(n0 + wr) * ldw + k0 + wkq);

    for (int kb = 0; kb < Kc; kb += 16) {
        __syncthreads();
        As[akq + 0][ar] = a0.x; As[akq + 1][ar] = a0.y; As[akq + 2][ar] = a0.z; As[akq + 3][ar] = a0.w;
        As[akq + 4][ar] = a1.x; As[akq + 5][ar] = a1.y; As[akq + 6][ar] = a1.z; As[akq + 7][ar] = a1.w;
        Ws[wkq + 0][wr] = w0.x; Ws[wkq + 1][wr] = w0.y; Ws[wkq + 2][wr] = w0.z; Ws[wkq + 3][wr] = w0.w;
        __syncthreads();
        if (kb + 16 < Kc) {
            a0 = *reinterpret_cast<const float4*>(A + (size_t)ar * lda + k0 + kb + 16 + akq);
            a1 = *reinterpret_cast<const float4*>(A + (size_t)ar * lda + k0 + kb + 16 + akq + 4);
            w0 = *reinterpret_cast<const float4*>(W + (size_t)(n0 + wr) * ldw + k0 + kb + 16 + wkq);
        }
#pragma unroll
        for (int kk = 0; kk < 16; ++kk) {
            float a[8], b[4];
#pragma unroll
            for (int i = 0; i < 8; ++i) a[i] = As[kk][ty * 8 + i];
#pragma unroll
            for (int j = 0; j < 4; ++j) b[j] = Ws[kk][tx * 4 + j];
#pragma unroll
            for (int i = 0; i < 8; ++i)
#pragma unroll
                for (int j = 0; j < 4; ++j) acc[i][j] = fmaf(a[i], b[j], acc[i][j]);
        }
    }

#pragma unroll
    for (int i = 0; i < 8; ++i) {
        const int m = ty * 8 + i;
#pragma unroll
        for (int j = 0; j < 4; ++j)
            P[((size_t)blockIdx.y * 128 + m) * N + n0 + tx * 4 + j] = acc[i][j];
    }
}

// ---------------------------------------------------------------------------
// W_ho GEMM with fused softmax-merge A-staging (Q=8), register-prefetched.
// ---------------------------------------------------------------------------
__global__ __launch_bounds__(256) void k_who(
    const float* __restrict__ pm, const float* __restrict__ pl,
    const float* __restrict__ pw, const float* __restrict__ hlstm,
    const float* __restrict__ W_ho,
    float* __restrict__ P, float* __restrict__ hist_t)
{
    __shared__ float As[16][128];
    __shared__ float Ws[16][64];
    __shared__ float eql[128][QS];
    const int n0 = blockIdx.x * 64;
    const int k0 = blockIdx.y * 128;
    const int t = threadIdx.x;
    const int tx = t & 15;
    const int ty = t >> 4;
    const int ar = t >> 1, akq = (t & 1) * 8;
    const int wr = t >> 2, wkq = (t & 3) * 4;
    const bool merge_side = (k0 < 512);
    const bool writer = (blockIdx.x == 0) && merge_side;

    if (merge_side && t < 128) {
        float mq[QS], eq[QS];
        float M = -INFINITY;
#pragma unroll
        for (int q = 0; q < QS; ++q) { mq[q] = pm[QS * t + q]; M = fmaxf(M, mq[q]); }
        float Lt = 0.f;
#pragma unroll
        for (int q = 0; q < QS; ++q) { eq[q] = __expf(mq[q] - M); Lt += eq[q] * pl[QS * t + q]; }
        float inv = 1.f / Lt;
#pragma unroll
        for (int q = 0; q < QS; ++q) eql[t][q] = eq[q] * inv;
    }
    __syncthreads();

    float acc[8][4] = {};
    float av[8];
    float4 w0;

    // load stage for a given kb
    auto load_stage = [&](int kb) {
        const int kg = k0 + kb + akq;
        if (merge_side) {
#pragma unroll
            for (int e = 0; e < 8; ++e) av[e] = 0.f;
#pragma unroll
            for (int q = 0; q < QS; ++q) {
                const float* pr = pw + (size_t)(QS * ar + q) * 512 + kg;
                float4 pa = *reinterpret_cast<const float4*>(pr);
                float4 pb = *reinterpret_cast<const float4*>(pr + 4);
                float qw = eql[ar][q];
                av[0] = fmaf(qw, pa.x, av[0]); av[1] = fmaf(qw, pa.y, av[1]);
                av[2] = fmaf(qw, pa.z, av[2]); av[3] = fmaf(qw, pa.w, av[3]);
                av[4] = fmaf(qw, pb.x, av[4]); av[5] = fmaf(qw, pb.y, av[5]);
                av[6] = fmaf(qw, pb.z, av[6]); av[7] = fmaf(qw, pb.w, av[7]);
            }
            if (writer) {
                *reinterpret_cast<float4*>(hist_t + (size_t)ar * 1024 + 512 + kg) = *reinterpret_cast<float4*>(&av[0]);
                *reinterpret_cast<float4*>(hist_t + (size_t)ar * 1024 + 512 + kg + 4) = *reinterpret_cast<float4*>(&av[4]);
            }
        } else {
            *reinterpret_cast<float4*>(&av[0]) = *reinterpret_cast<const float4*>(hlstm + (size_t)ar * 512 + kg - 512);
            *reinterpret_cast<float4*>(&av[4]) = *reinterpret_cast<const float4*>(hlstm + (size_t)ar * 512 + kg - 512 + 4);
        }
        w0 = *reinterpret_cast<const float4*>(W_ho + (size_t)(n0 + wr) * 1024 + k0 + kb + wkq);
    };

    load_stage(0);

    for (int kb = 0; kb < 128; kb += 16) {
        __syncthreads();
        As[akq + 0][ar] = av[0]; As[akq + 1][ar] = av[1]; As[akq + 2][ar] = av[2]; As[akq + 3][ar] = av[3];
        As[akq + 4][ar] = av[4]; As[akq + 5][ar] = av[5]; As[akq + 6][ar] = av[6]; As[akq + 7][ar] = av[7];
        Ws[wkq + 0][wr] = w0.x; Ws[wkq + 1][wr] = w0.y; Ws[wkq + 2][wr] = w0.z; Ws[wkq + 3][wr] = w0.w;
        __syncthreads();
        if (kb + 16 < 128) load_stage(kb + 16);
#pragma unroll
        for (int kk = 0; kk < 16; ++kk) {
            float a[8], b[4];
#pragma unroll
            for (int i = 0; i < 8; ++i) a[i] = As[kk][ty * 8 + i];
#pragma unroll
            for (int j = 0; j < 4; ++j) b[j] = Ws[kk][tx * 4 + j];
#pragma unroll
            for (int i = 0; i < 8; ++i)
#pragma unroll
                for (int j = 0; j < 4; ++j) acc[i][j] = fmaf(a[i], b[j], acc[i][j]);
        }
    }

#pragma unroll
    for (int i = 0; i < 8; ++i) {
        const int m = ty * 8 + i;
#pragma unroll
        for (int j = 0; j < 4; ++j)
            P[((size_t)blockIdx.y * 128 + m) * 512 + n0 + tx * 4 + j] = acc[i][j];
    }
}

// ---------------------------------------------------------------------------
__global__ void k_embed(const float* __restrict__ dec_in, const int* __restrict__ labels,
                        const float* __restrict__ emb, float* __restrict__ X)
{
    size_t total = (size_t)T_ * B_ * E_;
    for (size_t i = (size_t)blockIdx.x * blockDim.x + threadIdx.x; i < total;
         i += (size_t)gridDim.x * blockDim.x) {
        int e = (int)(i % E_);
        int b = (int)((i / E_) % B_);
        int t = (int)(i / ((size_t)E_ * B_));
        float v;
        if (t == 0) v = dec_in[b * E_ + e];
        else {
            int lab = labels[b * T_ + (t - 1)];
            v = emb[(size_t)lab * E_ + e];
        }
        X[i] = v;
    }
}

__global__ void k_init(const float* __restrict__ h0, const float* __restrict__ c0,
                       float* __restrict__ hbuf, float* __restrict__ cbuf)
{
    int i = blockIdx.x * blockDim.x + threadIdx.x;
    hbuf[i] = h0[i];
    cbuf[i] = c0[i];
}

// ---------------------------------------------------------------------------
// Attention (fp32 ctx): block (b, q of QS=8) handles 128 s-values.
// 8 waves x 16 s, register-prefetched; online softmax; partials (m,l,w[512]).
// ---------------------------------------------------------------------------
__global__ __launch_bounds__(512) void k_attn(const float* __restrict__ ctx,
    const float* __restrict__ Pa, const float* __restrict__ b_ain,
    const float* __restrict__ Vv,
    float* __restrict__ pm, float* __restrict__ pl, float* __restrict__ pw)
{
    int blk = blockIdx.x;
    int b = blk >> 3, q = blk & 7;
    int tid = threadIdx.x, lane = tid & 63, wv = tid >> 6;

    __shared__ float inp_sh[512];
    inp_sh[tid] = Pa[(size_t)b * 512 + tid]
                + Pa[(size_t)(128 + b) * 512 + tid]
                + Pa[(size_t)(256 + b) * 512 + tid]
                + Pa[(size_t)(384 + b) * 512 + tid]
                + b_ain[tid];
    __syncthreads();

    float inpr[8], vr[8];
    {
        const float4* v4 = reinterpret_cast<const float4*>(Vv) + lane * 2;
        *(float4*)&vr[0] = v4[0];   *(float4*)&vr[4] = v4[1];
#pragma unroll
        for (int k = 0; k < 8; ++k) inpr[k] = inp_sh[lane * 8 + k];
    }
    const float* sp = ctx + ((size_t)b * S_ + q * 128 + wv * 16) * H_ + lane * 8;

    float m = -INFINITY, l = 0.f, w[8] = {};
    float4 c0 = *reinterpret_cast<const float4*>(sp);
    float4 c1 = *reinterpret_cast<const float4*>(sp + 4);
    for (int si = 0; si < 16; ++si) {
        float4 u0 = c0, u1 = c1;
        if (si < 15) {
            c0 = *reinterpret_cast<const float4*>(sp + (size_t)(si + 1) * H_);
            c1 = *reinterpret_cast<const float4*>(sp + (size_t)(si + 1) * H_ + 4);
        }
        float c8[8];
        *(float4*)&c8[0] = u0; *(float4*)&c8[4] = u1;
        float t = 0.f;
#pragma unroll
        for (int k = 0; k < 8; ++k) t = fmaf(fast_tanhf_(inpr[k] + c8[k]), vr[k], t);
#pragma unroll
        for (int off = 32; off > 0; off >>= 1) t += __shfl_xor(t, off);
        float mn = fmaxf(m, t);
        float sc = __expf(m - mn);
        float p  = __expf(t - mn);
        l = l * sc + p;
#pragma unroll
        for (int k = 0; k < 8; ++k) w[k] = w[k] * sc + p * c8[k];
        m = mn;
    }

    __shared__ float wl[8 * 512];
    __shared__ float ml[8], ll[8];
#pragma unroll
    for (int k = 0; k < 8; ++k) wl[wv * 512 + lane * 8 + k] = w[k];
    if (lane == 0) { ml[wv] = m; ll[wv] = l; }
    __syncthreads();

    float M = ml[0];
#pragma unroll
    for (int u = 1; u < 8; ++u) M = fmaxf(M, ml[u]);
    float lt = 0.f, wt = 0.f;
#pragma unroll
    for (int u = 0; u < 8; ++u) {
        float e = __expf(ml[u] - M);
        lt += e * ll[u];
        wt += e * wl[u * 512 + tid];
    }
    if (tid == 0) { pm[blk] = M; pl[blk] = lt; }
    pw[(size_t)blk * 512 + tid] = wt;
}

// finalize W_ho: sum 8 partials + bias, tanh -> hbuf and hist_t[:,0:512]
__global__ __launch_bounds__(256) void k_whofin(const float* __restrict__ Po,
    const float* __restrict__ b_ho, float* __restrict__ hbuf, float* __restrict__ hist_t)
{
    int i = blockIdx.x * blockDim.x + threadIdx.x;
    int b = i >> 9, h = i & 511;
    float v = b_ho[h];
#pragma unroll
    for (int ks = 0; ks < 8; ++ks) v += Po[((size_t)ks * 128 + b) * 512 + h];
    v = tanhf(v);
    hbuf[i] = v;
    hist_t[(size_t)b * 1024 + h] = v;
}

__global__ __launch_bounds__(128) void k_argmax(const float* __restrict__ outp,
                                                float* __restrict__ preds)
{
    int row = blockIdx.x;
    int tid = threadIdx.x;
    float v = outp[(size_t)row * L_ + tid];
    int idx = tid;
#pragma unroll
    for (int off = 32; off > 0; off >>= 1) {
        float ov = __shfl_xor(v, off);
        int oi = __shfl_xor(idx, off);
        if (ov > v || (ov == v && oi < idx)) { v = ov; idx = oi; }
    }
    __shared__ float sv[2];
    __shared__ int si[2];
    if ((tid & 63) == 0) { sv[tid >> 6] = v; si[tid >> 6] = idx; }
    __syncthreads();
    if (tid == 0) {
        float v0 = sv[0], v1 = sv[1];
        int i0 = si[0], i1 = si[1];
        int r = (v1 > v0 || (v1 == v0 && i1 < i0)) ? i1 : i0;
        preds[row] = (float)r;
    }
}

__global__ void k_final(const float* __restrict__ hbuf, const float* __restrict__ cbuf,
                        float* __restrict__ hf, float* __restrict__ cf)
{
    int i = blockIdx.x * blockDim.x + threadIdx.x;
    hf[i] = hbuf[i];
    cf[i] = cbuf[i];
}

// ---------------------------------------------------------------------------
extern "C" void kernel_launch(void* const* d_in, const int* in_sizes, int n_in,
                              void* d_out, int out_size, void* d_ws, size_t ws_size,
                              hipStream_t stream)
{
    const float* dec_in  = (const float*)d_in[2];
    const float* h0      = (const float*)d_in[3];
    const float* c0      = (const float*)d_in[4];
    const float* context = (const float*)d_in[5];
    const int*   labels  = (const int*)d_in[6];
    const float* emb     = (const float*)d_in[8];
    const float* W_ih    = (const float*)d_in[9];
    const float* b_ih    = (const float*)d_in[10];
    const float* W_hh    = (const float*)d_in[11];
    const float* b_hh    = (const float*)d_in[12];
    const float* W_ho    = (const float*)d_in[13];
    const float* b_ho    = (const float*)d_in[14];
    const float* W_ain   = (const float*)d_in[15];
    const float* b_ain   = (const float*)d_in[16];
    const float* W_actx  = (const float*)d_in[17];
    const float* b_actx  = (const float*)d_in[18];
    const float* Vv      = (const float*)d_in[19];
    const float* W_out   = (const float*)d_in[20];
    const float* b_out   = (const float*)d_in[21];

    float* ws = (float*)d_ws;
    float* X     = ws; ws += (size_t)T_ * B_ * E_;
    float* xproj = ws; ws += (size_t)T_ * B_ * G4H;
    float* xout  = ws; ws += (size_t)T_ * B_ * L_;
    float* ctx   = ws; ws += (size_t)B_ * S_ * H_;
    float* hist  = ws; ws += (size_t)T_ * B_ * 1024;
    float* Wip   = ws; ws += (size_t)G4H * 512;
    float* Whp   = ws; ws += (size_t)G4H * 512;
    float* bp    = ws; ws += G4H;
    float* Pa    = ws; ws += (size_t)4 * B_ * H_;
    float* Po    = ws; ws += (size_t)8 * B_ * H_;
    float* cbuf  = ws; ws += (size_t)B_ * H_;
    float* hbuf  = ws; ws += (size_t)B_ * H_;
    float* hlstm = ws; ws += (size_t)B_ * H_;
    float* pm    = ws; ws += (size_t)B_ * QS;
    float* pl    = ws; ws += (size_t)B_ * QS;
    float* pw    = ws; ws += (size_t)B_ * QS * 512;

    float* out_logits = (float*)d_out;
    float* out_preds  = out_logits + (size_t)B_ * T_ * L_;
    float* out_hf     = out_preds + (size_t)B_ * T_;
    float* out_cf     = out_hf + (size_t)B_ * H_;

    // ---- precompute ----
    k_embed<<<2048, 256, 0, stream>>>(dec_in, labels, emb, X);
    k_init<<<256, 256, 0, stream>>>(h0, c0, hbuf, cbuf);
    k_perm<<<G4H, 128, 0, stream>>>(W_ih, W_hh, b_ih, b_hh, Wip, Whp, bp);
    gemm_split<<<dim3(16, 64), 256, 0, stream>>>(X, E_, Wip, E_, bp, nullptr, 0,
                                                 xproj, G4H, E_, 0, 0);
    gemm_split<<<dim3(1, 64), 256, 0, stream>>>(X, E_, W_out + 1024, 1536, b_out, nullptr, 0,
                                                xout, L_, E_, 0, 0);
    gemm_split<<<dim3(4, 1024), 256, 0, stream>>>(context, H_, W_actx, H_, b_actx, nullptr, 0,
                                                  ctx, H_, H_, 0, 0);

    // ---- sequential decode: 5 kernels/step ----
    for (int t = 0; t < T_; ++t) {
        float* hist_t = hist + (size_t)t * B_ * 1024;
        k_gateslstm<<<dim3(32, 4), 256, 0, stream>>>(hbuf, Whp,
                                                     xproj + (size_t)t * B_ * G4H,
                                                     cbuf, hlstm);
        gemm_stepk<<<dim3(8, 4), 256, 0, stream>>>(hlstm, H_, W_ain, H_, Pa, H_, 128);
        k_attn<<<B_ * QS, 512, 0, stream>>>(ctx, Pa, b_ain, Vv, pm, pl, pw);
        k_who<<<dim3(8, 8), 256, 0, stream>>>(pm, pl, pw, hlstm, W_ho, Po, hist_t);
        k_whofin<<<256, 256, 0, stream>>>(Po, b_ho, hbuf, hist_t);
    }

    // ---- deferred logits GEMM + argmax ----
    gemm_split<<<dim3(1, 64), 256, 0, stream>>>(hist, 1024, W_out, 1536, nullptr,
                                                xout, L_, out_logits, L_, 1024, 0, 1);
    k_argmax<<<B_ * T_, 128, 0, stream>>>(out_logits, out_preds);
    k_final<<<256, 256, 0, stream>>>(hbuf, cbuf, out_hf, out_cf);
}